// Round 4
// baseline (102.769 us; speedup 1.0000x reference)
//
#include <hip/hip_runtime.h>

// CRF loss on MI355X.
//   Z-part: exp-domain forward algorithm. exp(step matrix) = diag(g_t)*E with
//   g_t[i]=exp(sigmoid(h[t,b,i])), E=exp(trans)*2^-4 (per-step scale, corrected
//   by 4*ln2*len[b] at the end). L=1024 split into 16 chunks of 64 steps.
//   Phase 1: each wave owns FOUR chunks of one b (chains c = warp + 4i),
//   interleaved step-by-step so the serial MFMA chain has ILP=4 in-wave
//   (R3 post-mortem: 69us = ~82 cyc/step = bare chain latency, no hiding).
//   4 MFMAs per fused asm block -> hazard s_nops amortized 4x.
//   Phase 2: one wave per b combines 16 chunk matrices by matvec with
//   power-of-2 renorm. S-part: gather-sum of trans[y0[t+1],y0[t]]*mask[t].
// ws layout: [0,8KB) len, [8KB,16KB) S, [16KB,+16MB) P bf16.

typedef unsigned int u32;
typedef float f32x4 __attribute__((ext_vector_type(4)));
typedef short s16x4 __attribute__((ext_vector_type(4)));
typedef unsigned int u32x2 __attribute__((ext_vector_type(2)));

#define LOG2E 1.4426950408889634f
#define LN2   0.6931471805599453f
#define Bsz   2048
#define Lsz   1024
#define BT    32768   /* Bsz*16 floats per timestep */

#if __has_builtin(__builtin_amdgcn_exp2f)
__device__ __forceinline__ float exp2x(float x){ return __builtin_amdgcn_exp2f(x); }
#else
__device__ __forceinline__ float exp2x(float x){ return exp2f(x); }
#endif
#if __has_builtin(__builtin_amdgcn_logf)
__device__ __forceinline__ float log2x(float x){ return __builtin_amdgcn_logf(x); }
#else
__device__ __forceinline__ float log2x(float x){ return log2f(x); }
#endif
#if __has_builtin(__builtin_amdgcn_rcpf)
__device__ __forceinline__ float rcpx(float x){ return __builtin_amdgcn_rcpf(x); }
#else
__device__ __forceinline__ float rcpx(float x){ return 1.0f/x; }
#endif

__device__ __forceinline__ u32 cvtpk_bf16(float lo, float hi){
  u32 r;
  asm("v_cvt_pk_bf16_f32 %0, %1, %2" : "=v"(r) : "v"(lo), "v"(hi));
  return r;
}

// R1-proven single MFMA with hazard padding (used only for tail steps).
__device__ __forceinline__ f32x4 mfma16(s16x4 a, s16x4 b, f32x4 c){
  f32x4 d;
  asm volatile("s_nop 1\n\t"
      "v_mfma_f32_16x16x16_bf16 %0, %1, %2, %3\n\t"
      "s_nop 7\n\t"
      "s_nop 7"
      : "=&v"(d) : "v"(a), "v"(b), "v"(c));
  return d;
}

// Fused 4-chain MFMA: 4 independent products, one hazard-padding set.
// Margins match the proven single version: s_nop 1 covers VALU->MFMA-read for
// the last-written A/B; trailing s_nop 7 x2 gives d3 the same 16-cycle
// MFMA->VALU-read distance as mfma16 (d0..d2 get more).
__device__ __forceinline__ void mfma16x4(
    s16x4 a0, s16x4 a1, s16x4 a2, s16x4 a3,
    s16x4 b0, s16x4 b1, s16x4 b2, s16x4 b3,
    f32x4 z, f32x4& d0, f32x4& d1, f32x4& d2, f32x4& d3){
  asm volatile(
      "s_nop 1\n\t"
      "v_mfma_f32_16x16x16_bf16 %0, %4, %8, %12\n\t"
      "v_mfma_f32_16x16x16_bf16 %1, %5, %9, %12\n\t"
      "v_mfma_f32_16x16x16_bf16 %2, %6, %10, %12\n\t"
      "v_mfma_f32_16x16x16_bf16 %3, %7, %11, %12\n\t"
      "s_nop 7\n\t"
      "s_nop 7"
      : "=&v"(d0), "=&v"(d1), "=&v"(d2), "=&v"(d3)
      : "v"(a0), "v"(a1), "v"(a2), "v"(a3),
        "v"(b0), "v"(b1), "v"(b2), "v"(b3), "v"(z));
}

__global__ __launch_bounds__(256) void k_zero(float* lenw, float* Sw, float* out){
  int i = blockIdx.x*256 + threadIdx.x;
  if (i < Bsz) lenw[i] = 0.f;
  else if (i < 2*Bsz) Sw[i - Bsz] = 0.f;
  if (i == 0) out[0] = 0.f;
}

// lengths[b] = sum_t mask[t,b]; S[b] partial = sum_t trans[y0[t+1],y0[t]]*mask[t]
__global__ __launch_bounds__(256) void k_score(const int* __restrict__ y0,
    const float* __restrict__ mask, const float* __restrict__ trans,
    float* __restrict__ lenw, float* __restrict__ Sw){
  __shared__ float Tt[256];
  Tt[threadIdx.x] = trans[threadIdx.x];
  __syncthreads();
  int gid = blockIdx.x*256 + threadIdx.x;   // 65536 threads: b fast, tc slow
  int b  = gid & (Bsz-1);
  int tc = gid >> 11;                        // 0..31, 32 t's each
  int t0 = tc * 32;
  float lacc = 0.f, sacc = 0.f;
  int yc = y0[t0*Bsz + b];
  #pragma unroll 4
  for (int t = t0; t < t0+32; ++t) {
    float m = mask[t*Bsz + b];
    int yn = y0[(t+1)*Bsz + b];
    lacc += m;
    if (t <= Lsz-2) sacc += m * Tt[yn*16 + yc];
    yc = yn;
  }
  atomicAdd(&lenw[b], lacc);
  atomicAdd(&Sw[b], sacc);
}

// Phase 1: one block per b; wave = warp handles chunks {warp, warp+4, warp+8, warp+12}.
__global__ __launch_bounds__(256) void k_phase1(const float* __restrict__ h,
    const float* __restrict__ trans, const float* __restrict__ lenw,
    u32x2* __restrict__ Pout){
  // g staged as bf16 pairs: gbuf[warp*4+chain][cl][pair], pair p = (t/2),
  // u32 = (g_{2p}, g_{2p+1}). Row padded to 34 u32 (bank = 2cl+2r+{0,1} on
  // b64 reads -> conflict-free broadcast across grp).
  __shared__ u32 gbuf[16][16][34];
  int warp = threadIdx.x >> 6;
  int b    = blockIdx.x;
  int lane = threadIdx.x & 63;
  int cl   = lane & 15;          // A-row / B-col / D-col
  int grp  = lane >> 4;          // 0..3
  int len  = (int)(lenw[b] + 0.5f);

  int active[4], qc[4], tl[4];
  #pragma unroll
  for (int i = 0; i < 4; ++i) {
    int a = len - ((warp + 4*i) << 6);
    a = a < 0 ? 0 : (a > 64 ? 64 : a);
    active[i] = a; qc[i] = a >> 2; tl[i] = a & 3;
  }

  // ---- stage g = exp(sigmoid(h)) for 4 chunks, bf16-paired.
  // Lane (grp,cl) handles pairs p = 4u+grp (t = 8u+2grp, +1), own tag cl.
  #pragma unroll
  for (int i = 0; i < 4; ++i) {
    int t0 = (warp + 4*i) << 6;
    const float* hp = h + (size_t)t0*BT + b*16 + cl;
    u32* wrow = &gbuf[warp*4 + i][cl][0];
    #pragma unroll
    for (int u = 0; u < 8; ++u) {
      int tt = 8*u + 2*grp;
      float h0 = hp[(size_t)tt*BT];
      float h1 = hp[(size_t)(tt+1)*BT];
      float g0 = exp2x(rcpx(1.f + exp2x(h0 * (-LOG2E))) * LOG2E);
      float g1 = exp2x(rcpx(1.f + exp2x(h1 * (-LOG2E))) * LOG2E);
      wrow[4*u + grp] = cvtpk_bf16(g0, g1);
    }
  }
  // Same-wave ds_write -> ds_read: compiler inserts lgkmcnt wait (R3-proven).

  // E row cl, k-cols grp*4..+3, scaled by 2^-4. exp(NEG) underflows to 0.
  const float* tp = trans + cl*16 + grp*4;
  float E0 = exp2x(tp[0]*LOG2E) * 0.0625f;
  float E1 = exp2x(tp[1]*LOG2E) * 0.0625f;
  float E2 = exp2x(tp[2]*LOG2E) * 0.0625f;
  float E3 = exp2x(tp[3]*LOG2E) * 0.0625f;

  int k0 = grp*4;
  u32 ibx = ((k0+0)==cl ? 0x3F80u : 0u) | (((k0+1)==cl ? 0x3F80u : 0u) << 16);
  u32 iby = ((k0+2)==cl ? 0x3F80u : 0u) | (((k0+3)==cl ? 0x3F80u : 0u) << 16);
  u32 bx0=ibx, bx1=ibx, bx2=ibx, bx3=ibx;
  u32 by0=iby, by1=iby, by2=iby, by3=iby;
  u32 sx0=ibx, sx1=ibx, sx2=ibx, sx3=ibx;   // snapshots (init = identity)
  u32 sy0=iby, sy1=iby, sy2=iby, sy3=iby;
  const f32x4 z4 = {0.f, 0.f, 0.f, 0.f};

  const u32* r0 = &gbuf[warp*4 + 0][cl][0];
  const u32* r1 = &gbuf[warp*4 + 1][cl][0];
  const u32* r2 = &gbuf[warp*4 + 2][cl][0];
  const u32* r3 = &gbuf[warp*4 + 3][cl][0];

  for (int r = 0; r < 16; ++r) {
    u32x2 gp0 = *(const u32x2*)(r0 + 2*r);
    u32x2 gp1 = *(const u32x2*)(r1 + 2*r);
    u32x2 gp2 = *(const u32x2*)(r2 + 2*r);
    u32x2 gp3 = *(const u32x2*)(r3 + 2*r);
    #pragma unroll
    for (int q = 0; q < 4; ++q) {
      u32 w0 = (q < 2) ? gp0.x : gp0.y;
      u32 w1 = (q < 2) ? gp1.x : gp1.y;
      u32 w2 = (q < 2) ? gp2.x : gp2.y;
      u32 w3 = (q < 2) ? gp3.x : gp3.y;
      float g0 = __uint_as_float((q & 1) ? (w0 & 0xffff0000u) : (w0 << 16));
      float g1 = __uint_as_float((q & 1) ? (w1 & 0xffff0000u) : (w1 << 16));
      float g2 = __uint_as_float((q & 1) ? (w2 & 0xffff0000u) : (w2 << 16));
      float g3 = __uint_as_float((q & 1) ? (w3 & 0xffff0000u) : (w3 << 16));
      union { u32 u[2]; s16x4 v; } A0,A1,A2,A3, B0,B1,B2,B3;
      A0.u[0]=cvtpk_bf16(g0*E0,g0*E1); A0.u[1]=cvtpk_bf16(g0*E2,g0*E3);
      A1.u[0]=cvtpk_bf16(g1*E0,g1*E1); A1.u[1]=cvtpk_bf16(g1*E2,g1*E3);
      A2.u[0]=cvtpk_bf16(g2*E0,g2*E1); A2.u[1]=cvtpk_bf16(g2*E2,g2*E3);
      A3.u[0]=cvtpk_bf16(g3*E0,g3*E1); A3.u[1]=cvtpk_bf16(g3*E2,g3*E3);
      B0.u[0]=bx0; B0.u[1]=by0;  B1.u[0]=bx1; B1.u[1]=by1;
      B2.u[0]=bx2; B2.u[1]=by2;  B3.u[0]=bx3; B3.u[1]=by3;
      f32x4 d0,d1,d2,d3;
      mfma16x4(A0.v,A1.v,A2.v,A3.v, B0.v,B1.v,B2.v,B3.v, z4, d0,d1,d2,d3);
      bx0=cvtpk_bf16(d0.x,d0.y); by0=cvtpk_bf16(d0.z,d0.w);
      bx1=cvtpk_bf16(d1.x,d1.y); by1=cvtpk_bf16(d1.z,d1.w);
      bx2=cvtpk_bf16(d2.x,d2.y); by2=cvtpk_bf16(d2.z,d2.w);
      bx3=cvtpk_bf16(d3.x,d3.y); by3=cvtpk_bf16(d3.z,d3.w);
    }
    // snapshot at each chain's last full quad (wave-uniform conditions)
    if (r+1 == qc[0]) { sx0=bx0; sy0=by0; }
    if (r+1 == qc[1]) { sx1=bx1; sy1=by1; }
    if (r+1 == qc[2]) { sx2=bx2; sy2=by2; }
    if (r+1 == qc[3]) { sx3=bx3; sy3=by3; }
  }

  // tails (<=3 steps, at most ~1 chain per wave in practice) + stores
  u32 txa[4] = {sx0,sx1,sx2,sx3};
  u32 tya[4] = {sy0,sy1,sy2,sy3};
  const u32* rr[4] = {r0,r1,r2,r3};
  #pragma unroll
  for (int i = 0; i < 4; ++i) {
    u32 tbx = txa[i], tby = tya[i];
    if (tl[i] > 0) {
      u32x2 gp = *(const u32x2*)(rr[i] + 2*qc[i]);
      float ga = __uint_as_float(gp.x << 16);
      float gb = __uint_as_float(gp.x & 0xffff0000u);
      float gc = __uint_as_float(gp.y << 16);
      float gs[3] = {ga, gb, gc};
      for (int j = 0; j < tl[i]; ++j) {
        float g = gs[j];
        union { u32 u[2]; s16x4 v; } A, Bf;
        A.u[0] = cvtpk_bf16(g*E0, g*E1);
        A.u[1] = cvtpk_bf16(g*E2, g*E3);
        Bf.u[0] = tbx; Bf.u[1] = tby;
        f32x4 d = mfma16(A.v, Bf.v, z4);
        tbx = cvtpk_bf16(d.x, d.y);
        tby = cvtpk_bf16(d.z, d.w);
      }
    }
    if (active[i] > 0)
      Pout[(size_t)(b*16 + warp + 4*i)*64 + lane] = (u32x2){tbx, tby};
  }
}

// Phase 2: wave per b. v <- P_c * v with power-of-2 renorm; then final lse.
__global__ __launch_bounds__(256) void k_phase2(const u32x2* __restrict__ P,
    const float* __restrict__ trans, const float* __restrict__ lenw,
    const float* __restrict__ Sw, const int* __restrict__ y0,
    float* __restrict__ out){
  __shared__ float red[4];
  int b = blockIdx.x*4 + (threadIdx.x >> 6);
  int lane = threadIdx.x & 63;
  int cl = lane & 15, grp = lane >> 4;
  int len = (int)(lenw[b] + 0.5f);
  float v = (cl == 1) ? 1.f : 0.f;    // exp(Z0): one-hot at SOS_IDX=1
  float lsc = 0.f;                    // accumulated log2 scale
  int nch = (len + 63) >> 6;
  const u32x2* Pb = P + (size_t)b*16*64;
  int srcaddr = (cl >> 2) << 6;       // bpermute byte addr of lane (cl>>2)*16
  int msel = cl & 3;
  for (int c = 0; c < nch; ++c) {
    u32x2 pw = Pb[c*64 + lane];       // P[grp*4+m, cl] bf16 pairs
    float p0 = __uint_as_float(pw.x << 16);
    float p1 = __uint_as_float(pw.x & 0xffff0000u);
    float p2 = __uint_as_float(pw.y << 16);
    float p3 = __uint_as_float(pw.y & 0xffff0000u);
    float q0 = p0*v, q1 = p1*v, q2 = p2*v, q3 = p3*v;
    #pragma unroll
    for (int mk = 1; mk <= 8; mk <<= 1) {
      q0 += __shfl_xor(q0, mk);
      q1 += __shfl_xor(q1, mk);
      q2 += __shfl_xor(q2, mk);
      q3 += __shfl_xor(q3, mk);
    }
    float t0v = __int_as_float(__builtin_amdgcn_ds_bpermute(srcaddr, __float_as_int(q0)));
    float t1v = __int_as_float(__builtin_amdgcn_ds_bpermute(srcaddr, __float_as_int(q1)));
    float t2v = __int_as_float(__builtin_amdgcn_ds_bpermute(srcaddr, __float_as_int(q2)));
    float t3v = __int_as_float(__builtin_amdgcn_ds_bpermute(srcaddr, __float_as_int(q3)));
    float vn = (msel==0) ? t0v : (msel==1) ? t1v : (msel==2) ? t2v : t3v;
    float gm = fmaxf(fmaxf(q0,q1), fmaxf(q2,q3));
    gm = fmaxf(gm, __shfl_xor(gm, 16));
    gm = fmaxf(gm, __shfl_xor(gm, 32));
    int eb = (int)((__float_as_uint(gm) >> 23) & 0xff) - 127;
    float sc = __uint_as_float((u32)(127 - eb) << 23);
    v = vn * sc;
    lsc += (float)eb;
  }
  float eE = exp2x(trans[32 + cl] * LOG2E);
  float num = v * eE;
  num += __shfl_xor(num, 1);
  num += __shfl_xor(num, 2);
  num += __shfl_xor(num, 4);
  num += __shfl_xor(num, 8);
  if (lane == 0) {
    float Z = (log2x(num) + lsc + 4.f*(float)len) * LN2;
    int lastTag = y0[(size_t)len*Bsz + b];
    float Sb = Sw[b] + trans[lastTag];     // trans[PAD=0, lastTag]
    red[threadIdx.x >> 6] = (Z - Sb) * (1.f/(float)Bsz);
  }
  __syncthreads();
  if (threadIdx.x == 0) {
    atomicAdd(out, red[0] + red[1] + red[2] + red[3]);
  }
}

extern "C" void kernel_launch(void* const* d_in, const int* in_sizes, int n_in,
                              void* d_out, int out_size, void* d_ws, size_t ws_size,
                              hipStream_t stream) {
  const float* h     = (const float*)d_in[0];
  const int*   y0    = (const int*)d_in[1];
  const float* mask  = (const float*)d_in[2];
  const float* trans = (const float*)d_in[3];
  float* out  = (float*)d_out;
  float* lenw = (float*)d_ws;
  float* Sw   = lenw + Bsz;
  u32x2* P    = (u32x2*)((char*)d_ws + 16384);

  k_zero  <<<16,   256, 0, stream>>>(lenw, Sw, out);
  k_score <<<256,  256, 0, stream>>>(y0, mask, trans, lenw, Sw);
  k_phase1<<<2048, 256, 0, stream>>>(h, trans, lenw, P);
  k_phase2<<<512,  256, 0, stream>>>(P, trans, lenw, Sw, y0, out);
}

// Round 5
// 96.069 us; speedup vs baseline: 1.0697x; 1.0697x over previous
//
#include <hip/hip_runtime.h>

// CRF loss on MI355X.
//   Z-part: exp-domain forward algorithm. exp(step matrix) = diag(g_t)*E with
//   g_t[i]=exp(sigmoid(h[t,b,i])), E=exp(trans)*2^-4 (per-step scale, corrected
//   by 4*ln2*len[b] at the end). L=1024 split into 16 chunks of 64 steps.
//   Phase 1 (R5): wave owns FOUR chains = 4 consecutive b's, SAME chunk c
//   (ILP=4 on the serial MFMA chain), with chunk-major wave order
//   (wid -> c = wid>>9) restoring R1/R3's L3-resident h access (R4 post-mortem:
//   per-b mapping refetched all 134MB of h from HBM at 1.5 TB/s = the wall).
//   Staging reads are 256B-dense per instruction (lane = grp*16+cl).
//   Phase 2: one wave per b combines 16 chunk matrices by matvec with
//   power-of-2 renorm. S-part: gather-sum of trans[y0[t+1],y0[t]]*mask[t].
// ws layout: [0,8KB) len, [8KB,16KB) S, [16KB,+16MB) P bf16.

typedef unsigned int u32;
typedef float f32x4 __attribute__((ext_vector_type(4)));
typedef short s16x4 __attribute__((ext_vector_type(4)));
typedef unsigned int u32x2 __attribute__((ext_vector_type(2)));

#define LOG2E 1.4426950408889634f
#define LN2   0.6931471805599453f
#define Bsz   2048
#define Lsz   1024
#define BT    32768   /* Bsz*16 floats per timestep */

#if __has_builtin(__builtin_amdgcn_exp2f)
__device__ __forceinline__ float exp2x(float x){ return __builtin_amdgcn_exp2f(x); }
#else
__device__ __forceinline__ float exp2x(float x){ return exp2f(x); }
#endif
#if __has_builtin(__builtin_amdgcn_logf)
__device__ __forceinline__ float log2x(float x){ return __builtin_amdgcn_logf(x); }
#else
__device__ __forceinline__ float log2x(float x){ return log2f(x); }
#endif
#if __has_builtin(__builtin_amdgcn_rcpf)
__device__ __forceinline__ float rcpx(float x){ return __builtin_amdgcn_rcpf(x); }
#else
__device__ __forceinline__ float rcpx(float x){ return 1.0f/x; }
#endif

__device__ __forceinline__ u32 cvtpk_bf16(float lo, float hi){
  u32 r;
  asm("v_cvt_pk_bf16_f32 %0, %1, %2" : "=v"(r) : "v"(lo), "v"(hi));
  return r;
}

// R1-proven single MFMA with hazard padding (tail steps only).
__device__ __forceinline__ f32x4 mfma16(s16x4 a, s16x4 b, f32x4 c){
  f32x4 d;
  asm volatile("s_nop 1\n\t"
      "v_mfma_f32_16x16x16_bf16 %0, %1, %2, %3\n\t"
      "s_nop 7\n\t"
      "s_nop 7"
      : "=&v"(d) : "v"(a), "v"(b), "v"(c));
  return d;
}

// R4-proven fused 4-chain MFMA: 4 independent products, one hazard-padding set.
__device__ __forceinline__ void mfma16x4(
    s16x4 a0, s16x4 a1, s16x4 a2, s16x4 a3,
    s16x4 b0, s16x4 b1, s16x4 b2, s16x4 b3,
    f32x4 z, f32x4& d0, f32x4& d1, f32x4& d2, f32x4& d3){
  asm volatile(
      "s_nop 1\n\t"
      "v_mfma_f32_16x16x16_bf16 %0, %4, %8, %12\n\t"
      "v_mfma_f32_16x16x16_bf16 %1, %5, %9, %12\n\t"
      "v_mfma_f32_16x16x16_bf16 %2, %6, %10, %12\n\t"
      "v_mfma_f32_16x16x16_bf16 %3, %7, %11, %12\n\t"
      "s_nop 7\n\t"
      "s_nop 7"
      : "=&v"(d0), "=&v"(d1), "=&v"(d2), "=&v"(d3)
      : "v"(a0), "v"(a1), "v"(a2), "v"(a3),
        "v"(b0), "v"(b1), "v"(b2), "v"(b3), "v"(z));
}

__global__ __launch_bounds__(256) void k_zero(float* lenw, float* Sw, float* out){
  int i = blockIdx.x*256 + threadIdx.x;
  if (i < Bsz) lenw[i] = 0.f;
  else if (i < 2*Bsz) Sw[i - Bsz] = 0.f;
  if (i == 0) out[0] = 0.f;
}

// lengths[b] = sum_t mask[t,b]; S[b] partial = sum_t trans[y0[t+1],y0[t]]*mask[t]
__global__ __launch_bounds__(256) void k_score(const int* __restrict__ y0,
    const float* __restrict__ mask, const float* __restrict__ trans,
    float* __restrict__ lenw, float* __restrict__ Sw){
  __shared__ float Tt[256];
  Tt[threadIdx.x] = trans[threadIdx.x];
  __syncthreads();
  int gid = blockIdx.x*256 + threadIdx.x;   // 65536 threads: b fast, tc slow
  int b  = gid & (Bsz-1);
  int tc = gid >> 11;                        // 0..31, 32 t's each
  int t0 = tc * 32;
  float lacc = 0.f, sacc = 0.f;
  int yc = y0[t0*Bsz + b];
  #pragma unroll 4
  for (int t = t0; t < t0+32; ++t) {
    float m = mask[t*Bsz + b];
    int yn = y0[(t+1)*Bsz + b];
    lacc += m;
    if (t <= Lsz-2) sacc += m * Tt[yn*16 + yc];
    yc = yn;
  }
  atomicAdd(&lenw[b], lacc);
  atomicAdd(&Sw[b], sacc);
}

// Phase 1: wave wid = bid*4+warp; c = wid>>9 (chunk-major), b0 = (wid&511)*4.
// Chains i=0..3 <-> b0+i, all on chunk c.
__global__ __launch_bounds__(256) void k_phase1(const float* __restrict__ h,
    const float* __restrict__ trans, const float* __restrict__ lenw,
    u32x2* __restrict__ Pout){
  // g bf16 pairs: row s = warp*4+chain, index cl*34 + p (p = t/2, 32 pairs).
  // Row stride 545 dwords (545 = 17 mod 32) staggers banks:
  //  - ds_write (lanes grp,cl -> row warp*4+grp, same p): banks (17grp+2cl+p)&31
  //    -> grp0/2 on one parity, grp1/3 on other, 2-way max (free, m136).
  //  - main-loop b64 read (all lanes same row, pairs 2r..2r+1): 16 distinct
  //    b64 addrs spanning all 32 banks exactly once -> conflict-free.
  __shared__ u32 gbuf[16*545];
  int warp = threadIdx.x >> 6;
  int wid  = blockIdx.x*4 + warp;
  int c    = wid >> 9;           // 0..15 chunk (chunk-major across grid)
  int b0   = (wid & 511) << 2;   // 4 consecutive b's
  int lane = threadIdx.x & 63;
  int cl   = lane & 15;          // A-row / B-col / D-col
  int grp  = lane >> 4;          // 0..3
  int t0   = c << 6;

  int active[4], qc[4], tl[4];
  int amax = 0;
  #pragma unroll
  for (int i = 0; i < 4; ++i) {
    int a = (int)(lenw[b0 + i] + 0.5f) - t0;
    a = a < 0 ? 0 : (a > 64 ? 64 : a);
    active[i] = a; qc[i] = a >> 2; tl[i] = a & 3;
    amax = a > amax ? a : amax;
  }
  if (amax <= 0) return;         // whole wave past every chain's length

  // ---- stage g = exp(sigmoid(h)): per p, two 256B-dense loads (lane covers
  // h[t, b0*16 + lane]), convert, one ds_write u32 (bf16 pair) to own chain
  // row (chain = grp).
  {
    const float* hp = h + (size_t)t0*BT + b0*16 + lane;
    u32* wrow = &gbuf[(warp*4 + grp)*545 + cl*34];
    #pragma unroll 8
    for (int p = 0; p < 32; ++p) {
      float h0 = hp[(size_t)(2*p)*BT];
      float h1 = hp[(size_t)(2*p+1)*BT];
      float g0 = exp2x(rcpx(1.f + exp2x(h0 * (-LOG2E))) * LOG2E);
      float g1 = exp2x(rcpx(1.f + exp2x(h1 * (-LOG2E))) * LOG2E);
      wrow[p] = cvtpk_bf16(g0, g1);
    }
  }
  // Same-wave ds_write -> ds_read: compiler inserts lgkmcnt wait (R3/R4-proven).

  // E row cl, k-cols grp*4..+3, scaled by 2^-4. exp(NEG) underflows to 0.
  const float* tp = trans + cl*16 + grp*4;
  float E0 = exp2x(tp[0]*LOG2E) * 0.0625f;
  float E1 = exp2x(tp[1]*LOG2E) * 0.0625f;
  float E2 = exp2x(tp[2]*LOG2E) * 0.0625f;
  float E3 = exp2x(tp[3]*LOG2E) * 0.0625f;

  int k0 = grp*4;
  u32 ibx = ((k0+0)==cl ? 0x3F80u : 0u) | (((k0+1)==cl ? 0x3F80u : 0u) << 16);
  u32 iby = ((k0+2)==cl ? 0x3F80u : 0u) | (((k0+3)==cl ? 0x3F80u : 0u) << 16);
  u32 bx0=ibx, bx1=ibx, bx2=ibx, bx3=ibx;
  u32 by0=iby, by1=iby, by2=iby, by3=iby;
  u32 sx0=ibx, sx1=ibx, sx2=ibx, sx3=ibx;   // snapshots (init = identity)
  u32 sy0=iby, sy1=iby, sy2=iby, sy3=iby;
  const f32x4 z4 = {0.f, 0.f, 0.f, 0.f};

  const u32* r0 = &gbuf[(warp*4 + 0)*545 + cl*34];
  const u32* r1 = &gbuf[(warp*4 + 1)*545 + cl*34];
  const u32* r2 = &gbuf[(warp*4 + 2)*545 + cl*34];
  const u32* r3 = &gbuf[(warp*4 + 3)*545 + cl*34];

  int R = (amax + 3) >> 2;       // full-quad iters (wave-uniform)
  for (int r = 0; r < R; ++r) {
    u32x2 gp0 = *(const u32x2*)(r0 + 2*r);
    u32x2 gp1 = *(const u32x2*)(r1 + 2*r);
    u32x2 gp2 = *(const u32x2*)(r2 + 2*r);
    u32x2 gp3 = *(const u32x2*)(r3 + 2*r);
    #pragma unroll
    for (int q = 0; q < 4; ++q) {
      u32 w0 = (q < 2) ? gp0.x : gp0.y;
      u32 w1 = (q < 2) ? gp1.x : gp1.y;
      u32 w2 = (q < 2) ? gp2.x : gp2.y;
      u32 w3 = (q < 2) ? gp3.x : gp3.y;
      float g0 = __uint_as_float((q & 1) ? (w0 & 0xffff0000u) : (w0 << 16));
      float g1 = __uint_as_float((q & 1) ? (w1 & 0xffff0000u) : (w1 << 16));
      float g2 = __uint_as_float((q & 1) ? (w2 & 0xffff0000u) : (w2 << 16));
      float g3 = __uint_as_float((q & 1) ? (w3 & 0xffff0000u) : (w3 << 16));
      union { u32 u[2]; s16x4 v; } A0,A1,A2,A3, B0,B1,B2,B3;
      A0.u[0]=cvtpk_bf16(g0*E0,g0*E1); A0.u[1]=cvtpk_bf16(g0*E2,g0*E3);
      A1.u[0]=cvtpk_bf16(g1*E0,g1*E1); A1.u[1]=cvtpk_bf16(g1*E2,g1*E3);
      A2.u[0]=cvtpk_bf16(g2*E0,g2*E1); A2.u[1]=cvtpk_bf16(g2*E2,g2*E3);
      A3.u[0]=cvtpk_bf16(g3*E0,g3*E1); A3.u[1]=cvtpk_bf16(g3*E2,g3*E3);
      B0.u[0]=bx0; B0.u[1]=by0;  B1.u[0]=bx1; B1.u[1]=by1;
      B2.u[0]=bx2; B2.u[1]=by2;  B3.u[0]=bx3; B3.u[1]=by3;
      f32x4 d0,d1,d2,d3;
      mfma16x4(A0.v,A1.v,A2.v,A3.v, B0.v,B1.v,B2.v,B3.v, z4, d0,d1,d2,d3);
      bx0=cvtpk_bf16(d0.x,d0.y); by0=cvtpk_bf16(d0.z,d0.w);
      bx1=cvtpk_bf16(d1.x,d1.y); by1=cvtpk_bf16(d1.z,d1.w);
      bx2=cvtpk_bf16(d2.x,d2.y); by2=cvtpk_bf16(d2.z,d2.w);
      bx3=cvtpk_bf16(d3.x,d3.y); by3=cvtpk_bf16(d3.z,d3.w);
    }
    // snapshot at each chain's last full quad (wave-uniform conditions)
    if (r+1 == qc[0]) { sx0=bx0; sy0=by0; }
    if (r+1 == qc[1]) { sx1=bx1; sy1=by1; }
    if (r+1 == qc[2]) { sx2=bx2; sy2=by2; }
    if (r+1 == qc[3]) { sx3=bx3; sy3=by3; }
  }

  // tails (<=3 steps per chain) + stores
  u32 txa[4] = {sx0,sx1,sx2,sx3};
  u32 tya[4] = {sy0,sy1,sy2,sy3};
  const u32* rr[4] = {r0,r1,r2,r3};
  #pragma unroll
  for (int i = 0; i < 4; ++i) {
    u32 tbx = txa[i], tby = tya[i];
    if (tl[i] > 0) {
      u32x2 gp = *(const u32x2*)(rr[i] + 2*qc[i]);
      float ga = __uint_as_float(gp.x << 16);
      float gb = __uint_as_float(gp.x & 0xffff0000u);
      float gc = __uint_as_float(gp.y << 16);
      float gs[3] = {ga, gb, gc};
      for (int j = 0; j < tl[i]; ++j) {
        float g = gs[j];
        union { u32 u[2]; s16x4 v; } A, Bf;
        A.u[0] = cvtpk_bf16(g*E0, g*E1);
        A.u[1] = cvtpk_bf16(g*E2, g*E3);
        Bf.u[0] = tbx; Bf.u[1] = tby;
        f32x4 d = mfma16(A.v, Bf.v, z4);
        tbx = cvtpk_bf16(d.x, d.y);
        tby = cvtpk_bf16(d.z, d.w);
      }
    }
    if (active[i] > 0)
      Pout[((size_t)(b0 + i)*16 + c)*64 + lane] = (u32x2){tbx, tby};
  }
}

// Phase 2: wave per b. v <- P_c * v with power-of-2 renorm; then final lse.
__global__ __launch_bounds__(256) void k_phase2(const u32x2* __restrict__ P,
    const float* __restrict__ trans, const float* __restrict__ lenw,
    const float* __restrict__ Sw, const int* __restrict__ y0,
    float* __restrict__ out){
  __shared__ float red[4];
  int b = blockIdx.x*4 + (threadIdx.x >> 6);
  int lane = threadIdx.x & 63;
  int cl = lane & 15, grp = lane >> 4;
  int len = (int)(lenw[b] + 0.5f);
  float v = (cl == 1) ? 1.f : 0.f;    // exp(Z0): one-hot at SOS_IDX=1
  float lsc = 0.f;                    // accumulated log2 scale
  int nch = (len + 63) >> 6;
  const u32x2* Pb = P + (size_t)b*16*64;
  int srcaddr = (cl >> 2) << 6;       // bpermute byte addr of lane (cl>>2)*16
  int msel = cl & 3;
  for (int c = 0; c < nch; ++c) {
    u32x2 pw = Pb[c*64 + lane];       // P[grp*4+m, cl] bf16 pairs
    float p0 = __uint_as_float(pw.x << 16);
    float p1 = __uint_as_float(pw.x & 0xffff0000u);
    float p2 = __uint_as_float(pw.y << 16);
    float p3 = __uint_as_float(pw.y & 0xffff0000u);
    float q0 = p0*v, q1 = p1*v, q2 = p2*v, q3 = p3*v;
    #pragma unroll
    for (int mk = 1; mk <= 8; mk <<= 1) {
      q0 += __shfl_xor(q0, mk);
      q1 += __shfl_xor(q1, mk);
      q2 += __shfl_xor(q2, mk);
      q3 += __shfl_xor(q3, mk);
    }
    float t0v = __int_as_float(__builtin_amdgcn_ds_bpermute(srcaddr, __float_as_int(q0)));
    float t1v = __int_as_float(__builtin_amdgcn_ds_bpermute(srcaddr, __float_as_int(q1)));
    float t2v = __int_as_float(__builtin_amdgcn_ds_bpermute(srcaddr, __float_as_int(q2)));
    float t3v = __int_as_float(__builtin_amdgcn_ds_bpermute(srcaddr, __float_as_int(q3)));
    float vn = (msel==0) ? t0v : (msel==1) ? t1v : (msel==2) ? t2v : t3v;
    float gm = fmaxf(fmaxf(q0,q1), fmaxf(q2,q3));
    gm = fmaxf(gm, __shfl_xor(gm, 16));
    gm = fmaxf(gm, __shfl_xor(gm, 32));
    int eb = (int)((__float_as_uint(gm) >> 23) & 0xff) - 127;
    float sc = __uint_as_float((u32)(127 - eb) << 23);
    v = vn * sc;
    lsc += (float)eb;
  }
  float eE = exp2x(trans[32 + cl] * LOG2E);
  float num = v * eE;
  num += __shfl_xor(num, 1);
  num += __shfl_xor(num, 2);
  num += __shfl_xor(num, 4);
  num += __shfl_xor(num, 8);
  if (lane == 0) {
    float Z = (log2x(num) + lsc + 4.f*(float)len) * LN2;
    int lastTag = y0[(size_t)len*Bsz + b];
    float Sb = Sw[b] + trans[lastTag];     // trans[PAD=0, lastTag]
    red[threadIdx.x >> 6] = (Z - Sb) * (1.f/(float)Bsz);
  }
  __syncthreads();
  if (threadIdx.x == 0) {
    atomicAdd(out, red[0] + red[1] + red[2] + red[3]);
  }
}

extern "C" void kernel_launch(void* const* d_in, const int* in_sizes, int n_in,
                              void* d_out, int out_size, void* d_ws, size_t ws_size,
                              hipStream_t stream) {
  const float* h     = (const float*)d_in[0];
  const int*   y0    = (const int*)d_in[1];
  const float* mask  = (const float*)d_in[2];
  const float* trans = (const float*)d_in[3];
  float* out  = (float*)d_out;
  float* lenw = (float*)d_ws;
  float* Sw   = lenw + Bsz;
  u32x2* P    = (u32x2*)((char*)d_ws + 16384);

  k_zero  <<<16,   256, 0, stream>>>(lenw, Sw, out);
  k_score <<<256,  256, 0, stream>>>(y0, mask, trans, lenw, Sw);
  k_phase1<<<2048, 256, 0, stream>>>(h, trans, lenw, P);
  k_phase2<<<512,  256, 0, stream>>>(P, trans, lenw, Sw, y0, out);
}

// Round 6
// 87.239 us; speedup vs baseline: 1.1780x; 1.1012x over previous
//
#include <hip/hip_runtime.h>

// CRF loss on MI355X.
//   Z-part: exp-domain forward algorithm. exp(step matrix) = diag(g_t)*E with
//   g_t[i]=exp(sigmoid(h[t,b,i])), E=exp(trans)*2^-4 (per-step scale, corrected
//   by 4*ln2*len[b] at the end). L=1024 split into 16 chunks of 64 steps.
//   Phase 1 (R6): wave per (b,chunk), chunk-major order (L3-warm h, proven
//   R3/R5). KEY refactor vs R1-R5: Em_t*V = diag(g_t)*(E*V), so the MFMA runs
//   with CONSTANT A = E (bf16, built once) and diag(g_t) is applied to D
//   during the already-required D->B repack: V = d * g4 (one broadcast
//   ds_read_b128 of g[t][4grp..+3]) then 2 cvtpk. Per-step cost drops from
//   ~28 VALU-equiv (R5 measured) to ~6 VALU + 1 DS + 1 MFMA.
//   Phase 2: one wave per b combines 16 chunk matrices by matvec with
//   power-of-2 renorm. S-part: gather-sum of trans[y0[t+1],y0[t]]*mask[t].
// ws layout: [0,8KB) len, [8KB,16KB) S, [16KB,+16MB) P bf16.

typedef unsigned int u32;
typedef float f32x4 __attribute__((ext_vector_type(4)));
typedef short s16x4 __attribute__((ext_vector_type(4)));
typedef unsigned int u32x2 __attribute__((ext_vector_type(2)));

#define LOG2E 1.4426950408889634f
#define LN2   0.6931471805599453f
#define Bsz   2048
#define Lsz   1024
#define BT    32768   /* Bsz*16 floats per timestep */
#define GSTR  20      /* g row stride in floats: 80B = 5*16B -> b128-aligned */

#if __has_builtin(__builtin_amdgcn_exp2f)
__device__ __forceinline__ float exp2x(float x){ return __builtin_amdgcn_exp2f(x); }
#else
__device__ __forceinline__ float exp2x(float x){ return exp2f(x); }
#endif
#if __has_builtin(__builtin_amdgcn_logf)
__device__ __forceinline__ float log2x(float x){ return __builtin_amdgcn_logf(x); }
#else
__device__ __forceinline__ float log2x(float x){ return log2f(x); }
#endif
#if __has_builtin(__builtin_amdgcn_rcpf)
__device__ __forceinline__ float rcpx(float x){ return __builtin_amdgcn_rcpf(x); }
#else
__device__ __forceinline__ float rcpx(float x){ return 1.0f/x; }
#endif

__device__ __forceinline__ u32 cvtpk_bf16(float lo, float hi){
  u32 r;
  asm("v_cvt_pk_bf16_f32 %0, %1, %2" : "=v"(r) : "v"(lo), "v"(hi));
  return r;
}

// R1-proven inline-asm MFMA with conservative hazard padding.
__device__ __forceinline__ f32x4 mfma16(s16x4 a, s16x4 b, f32x4 c){
  f32x4 d;
  asm volatile("s_nop 1\n\t"
      "v_mfma_f32_16x16x16_bf16 %0, %1, %2, %3\n\t"
      "s_nop 7\n\t"
      "s_nop 7"
      : "=&v"(d) : "v"(a), "v"(b), "v"(c));
  return d;
}

__global__ __launch_bounds__(256) void k_zero(float* lenw, float* Sw, float* out){
  int i = blockIdx.x*256 + threadIdx.x;
  if (i < Bsz) lenw[i] = 0.f;
  else if (i < 2*Bsz) Sw[i - Bsz] = 0.f;
  if (i == 0) out[0] = 0.f;
}

// lengths[b] = sum_t mask[t,b]; S[b] partial = sum_t trans[y0[t+1],y0[t]]*mask[t]
__global__ __launch_bounds__(256) void k_score(const int* __restrict__ y0,
    const float* __restrict__ mask, const float* __restrict__ trans,
    float* __restrict__ lenw, float* __restrict__ Sw){
  __shared__ float Tt[256];
  Tt[threadIdx.x] = trans[threadIdx.x];
  __syncthreads();
  int gid = blockIdx.x*256 + threadIdx.x;   // 65536 threads: b fast, tc slow
  int b  = gid & (Bsz-1);
  int tc = gid >> 11;                        // 0..31, 32 t's each
  int t0 = tc * 32;
  float lacc = 0.f, sacc = 0.f;
  int yc = y0[t0*Bsz + b];
  #pragma unroll 4
  for (int t = t0; t < t0+32; ++t) {
    float m = mask[t*Bsz + b];
    int yn = y0[(t+1)*Bsz + b];
    lacc += m;
    if (t <= Lsz-2) sacc += m * Tt[yn*16 + yc];
    yc = yn;
  }
  atomicAdd(&lenw[b], lacc);
  atomicAdd(&Sw[b], sacc);
}

// Phase 1: wave wid = bid*4+warp; c = wid>>11 (chunk-major), b = wid&2047.
__global__ __launch_bounds__(256) void k_phase1(const float* __restrict__ h,
    const float* __restrict__ trans, const float* __restrict__ lenw,
    u32x2* __restrict__ Pout){
  // per-warp g tile, f32, [t][tag] with row stride 20 (80B = 5x16B):
  //  - hot-path read: b128 at idx t*20 + grp*4 -> 4 broadcast addrs spanning
  //    16 consecutive banks, conflict-free.
  //  - staging write: b32 at idx t*20+cl, <=3-way aliasing (cold path).
  __shared__ __align__(16) float gbuf[4][65*GSTR];
  int warp = threadIdx.x >> 6;
  int wid  = blockIdx.x*4 + warp;
  int c    = wid >> 11;          // 0..15 chunk (chunk-major across grid)
  int b    = wid & (Bsz-1);
  int lane = threadIdx.x & 63;
  int cl   = lane & 15;          // A-row / B-col / D-col
  int grp  = lane >> 4;          // 0..3
  int t0   = c << 6;
  int len  = (int)(lenw[b] + 0.5f);
  int active = len - t0;
  if (active <= 0) return;       // chunk fully masked: phase 2 skips it
  if (active > 64) active = 64;

  // ---- stage g = exp(sigmoid(h)) f32 for the whole 64-step chunk.
  // Lane (grp,cl) handles t = 4i+grp, tag cl (R3-proven dense pattern).
  {
    const float* hp = h + (size_t)(t0 + grp)*BT + b*16 + cl;
    float* wp = &gbuf[warp][0];
    #pragma unroll
    for (int i = 0; i < 16; ++i) {
      float hv = hp[(size_t)(4*i)*BT];
      float sg = rcpx(1.f + exp2x(hv * (-LOG2E)));
      wp[(4*i + grp)*GSTR + cl] = exp2x(sg * LOG2E);
    }
  }
  // Same-wave ds_write -> ds_read: compiler inserts lgkmcnt wait (proven).

  // Constant A = E (row cl, k-cols grp*4..+3), scaled 2^-4, bf16. Built once.
  union { u32 u[2]; s16x4 v; } EA;
  {
    const float* tp = trans + cl*16 + grp*4;
    float E0 = exp2x(tp[0]*LOG2E) * 0.0625f;
    float E1 = exp2x(tp[1]*LOG2E) * 0.0625f;
    float E2 = exp2x(tp[2]*LOG2E) * 0.0625f;
    float E3 = exp2x(tp[3]*LOG2E) * 0.0625f;
    EA.u[0] = cvtpk_bf16(E0, E1);
    EA.u[1] = cvtpk_bf16(E2, E3);
  }

  // Running product B operand, init = identity (bf16 1.0 = 0x3F80)
  int k0 = grp*4;
  u32 bx = ((k0+0)==cl ? 0x3F80u : 0u) | (((k0+1)==cl ? 0x3F80u : 0u) << 16);
  u32 by = ((k0+2)==cl ? 0x3F80u : 0u) | (((k0+3)==cl ? 0x3F80u : 0u) << 16);
  const f32x4 z4 = {0.f, 0.f, 0.f, 0.f};

  // g pointer for this lane's D rows (rows grp*4..+3 of D <-> g[t][4grp+j])
  const float* gp = &gbuf[warp][grp*4];

  f32x4 gc = *(const f32x4*)(gp);          // g for step 0
  #pragma unroll 2
  for (int s = 0; s < active; ++s) {
    // prefetch next step's g before the MFMA (row s+1 <= 64 always exists;
    // final iteration's value is discarded)
    f32x4 gn = *(const f32x4*)(gp + (s+1)*GSTR);
    union { u32 u[2]; s16x4 v; } Bf;
    Bf.u[0] = bx; Bf.u[1] = by;
    f32x4 d = mfma16(EA.v, Bf.v, z4);      // W = E * V
    float v0 = d.x*gc.x, v1 = d.y*gc.y;    // V = diag(g_t) * W
    float v2 = d.z*gc.z, v3 = d.w*gc.w;
    bx = cvtpk_bf16(v0, v1);
    by = cvtpk_bf16(v2, v3);
    gc = gn;
  }

  Pout[(size_t)(b*16 + c)*64 + lane] = (u32x2){bx, by};
}

// Phase 2: wave per b. v <- P_c * v with power-of-2 renorm; then final lse.
__global__ __launch_bounds__(256) void k_phase2(const u32x2* __restrict__ P,
    const float* __restrict__ trans, const float* __restrict__ lenw,
    const float* __restrict__ Sw, const int* __restrict__ y0,
    float* __restrict__ out){
  __shared__ float red[4];
  int b = blockIdx.x*4 + (threadIdx.x >> 6);
  int lane = threadIdx.x & 63;
  int cl = lane & 15, grp = lane >> 4;
  int len = (int)(lenw[b] + 0.5f);
  float v = (cl == 1) ? 1.f : 0.f;    // exp(Z0): one-hot at SOS_IDX=1
  float lsc = 0.f;                    // accumulated log2 scale
  int nch = (len + 63) >> 6;
  const u32x2* Pb = P + (size_t)b*16*64;
  int srcaddr = (cl >> 2) << 6;       // bpermute byte addr of lane (cl>>2)*16
  int msel = cl & 3;
  for (int c = 0; c < nch; ++c) {
    u32x2 pw = Pb[c*64 + lane];       // P[grp*4+m, cl] bf16 pairs
    float p0 = __uint_as_float(pw.x << 16);
    float p1 = __uint_as_float(pw.x & 0xffff0000u);
    float p2 = __uint_as_float(pw.y << 16);
    float p3 = __uint_as_float(pw.y & 0xffff0000u);
    float q0 = p0*v, q1 = p1*v, q2 = p2*v, q3 = p3*v;
    #pragma unroll
    for (int mk = 1; mk <= 8; mk <<= 1) {
      q0 += __shfl_xor(q0, mk);
      q1 += __shfl_xor(q1, mk);
      q2 += __shfl_xor(q2, mk);
      q3 += __shfl_xor(q3, mk);
    }
    float t0v = __int_as_float(__builtin_amdgcn_ds_bpermute(srcaddr, __float_as_int(q0)));
    float t1v = __int_as_float(__builtin_amdgcn_ds_bpermute(srcaddr, __float_as_int(q1)));
    float t2v = __int_as_float(__builtin_amdgcn_ds_bpermute(srcaddr, __float_as_int(q2)));
    float t3v = __int_as_float(__builtin_amdgcn_ds_bpermute(srcaddr, __float_as_int(q3)));
    float vn = (msel==0) ? t0v : (msel==1) ? t1v : (msel==2) ? t2v : t3v;
    float gm = fmaxf(fmaxf(q0,q1), fmaxf(q2,q3));
    gm = fmaxf(gm, __shfl_xor(gm, 16));
    gm = fmaxf(gm, __shfl_xor(gm, 32));
    int eb = (int)((__float_as_uint(gm) >> 23) & 0xff) - 127;
    float sc = __uint_as_float((u32)(127 - eb) << 23);
    v = vn * sc;
    lsc += (float)eb;
  }
  float eE = exp2x(trans[32 + cl] * LOG2E);
  float num = v * eE;
  num += __shfl_xor(num, 1);
  num += __shfl_xor(num, 2);
  num += __shfl_xor(num, 4);
  num += __shfl_xor(num, 8);
  if (lane == 0) {
    float Z = (log2x(num) + lsc + 4.f*(float)len) * LN2;
    int lastTag = y0[(size_t)len*Bsz + b];
    float Sb = Sw[b] + trans[lastTag];     // trans[PAD=0, lastTag]
    red[threadIdx.x >> 6] = (Z - Sb) * (1.f/(float)Bsz);
  }
  __syncthreads();
  if (threadIdx.x == 0) {
    atomicAdd(out, red[0] + red[1] + red[2] + red[3]);
  }
}

extern "C" void kernel_launch(void* const* d_in, const int* in_sizes, int n_in,
                              void* d_out, int out_size, void* d_ws, size_t ws_size,
                              hipStream_t stream) {
  const float* h     = (const float*)d_in[0];
  const int*   y0    = (const int*)d_in[1];
  const float* mask  = (const float*)d_in[2];
  const float* trans = (const float*)d_in[3];
  float* out  = (float*)d_out;
  float* lenw = (float*)d_ws;
  float* Sw   = lenw + Bsz;
  u32x2* P    = (u32x2*)((char*)d_ws + 16384);

  k_zero  <<<16,   256, 0, stream>>>(lenw, Sw, out);
  k_score <<<256,  256, 0, stream>>>(y0, mask, trans, lenw, Sw);
  k_phase1<<<8192, 256, 0, stream>>>(h, trans, lenw, P);
  k_phase2<<<512,  256, 0, stream>>>(P, trans, lenw, Sw, y0, out);
}